// Round 1
// baseline (553.820 us; speedup 1.0000x reference)
//
#include <hip/hip_runtime.h>
#include <math.h>

#define NEG_SLOPE 0.2f

// ---------------------------------------------------------------------------
// GEMM: feat = x @ fc_w^T  (N x 128) = (N x 128) @ (128 x 128)^T
// fused epilogue: el[n][h] = sum_d feat[n][h*32+d]*attn_l[h][d], er likewise.
// Block = 256 threads, tile = 128 rows. fc_w staged transposed in LDS [k][c].
// Thread (rgrp=t>>3, g=t&7): rows rgrp+32*i (i<4), cols 4g+32*j2+m (j2<4,m<4).
// ---------------------------------------------------------------------------
__global__ __launch_bounds__(256) void gemm_feat_attn(
    const float* __restrict__ x, const float* __restrict__ fc_w,
    const float* __restrict__ attn_l, const float* __restrict__ attn_r,
    float* __restrict__ feat, float* __restrict__ el, float* __restrict__ er,
    int N)
{
  __shared__ float fc_lds[128 * 128];  // [k][c]; bank = c%32 -> conflict-free
  const int t = threadIdx.x;
  // Stage fc transposed. c = f&127 (lane-consecutive -> conflict-free LDS
  // writes); global reads are strided but fc is only 64 KB (L2-resident).
  for (int f = t; f < 128 * 32; f += 256) {
    const int c = f & 127, k4 = f >> 7;
    const float4 v = *reinterpret_cast<const float4*>(fc_w + c * 128 + k4 * 4);
    fc_lds[(k4 * 4 + 0) * 128 + c] = v.x;
    fc_lds[(k4 * 4 + 1) * 128 + c] = v.y;
    fc_lds[(k4 * 4 + 2) * 128 + c] = v.z;
    fc_lds[(k4 * 4 + 3) * 128 + c] = v.w;
  }
  __syncthreads();

  const int rgrp = t >> 3;  // [0,32)
  const int g = t & 7;      // [0,8)
  const int row_base = blockIdx.x * 128;

  float acc[4][16];
#pragma unroll
  for (int i = 0; i < 4; ++i)
#pragma unroll
    for (int j = 0; j < 16; ++j) acc[i][j] = 0.f;

  int r[4]; bool valid[4]; const float* xp[4];
#pragma unroll
  for (int i = 0; i < 4; ++i) {
    r[i] = row_base + rgrp + 32 * i;
    valid[i] = r[i] < N;
    xp[i] = x + (size_t)(valid[i] ? r[i] : 0) * 128;
  }

  for (int k = 0; k < 128; k += 4) {
    float4 xv[4];
#pragma unroll
    for (int i = 0; i < 4; ++i)
      xv[i] = *reinterpret_cast<const float4*>(xp[i] + k);
#pragma unroll
    for (int kk = 0; kk < 4; ++kk) {
      float4 fv[4];
#pragma unroll
      for (int j2 = 0; j2 < 4; ++j2)
        fv[j2] = *reinterpret_cast<const float4*>(
            &fc_lds[(k + kk) * 128 + 4 * g + 32 * j2]);
#pragma unroll
      for (int i = 0; i < 4; ++i) {
        const float xs = (kk == 0) ? xv[i].x : (kk == 1) ? xv[i].y
                       : (kk == 2) ? xv[i].z : xv[i].w;
#pragma unroll
        for (int j2 = 0; j2 < 4; ++j2) {
          acc[i][j2 * 4 + 0] = fmaf(xs, fv[j2].x, acc[i][j2 * 4 + 0]);
          acc[i][j2 * 4 + 1] = fmaf(xs, fv[j2].y, acc[i][j2 * 4 + 1]);
          acc[i][j2 * 4 + 2] = fmaf(xs, fv[j2].z, acc[i][j2 * 4 + 2]);
          acc[i][j2 * 4 + 3] = fmaf(xs, fv[j2].w, acc[i][j2 * 4 + 3]);
        }
      }
    }
  }

  // store feat (float4 per col-group)
#pragma unroll
  for (int i = 0; i < 4; ++i) {
    if (!valid[i]) continue;
#pragma unroll
    for (int j2 = 0; j2 < 4; ++j2) {
      const float4 v = make_float4(acc[i][j2 * 4 + 0], acc[i][j2 * 4 + 1],
                                   acc[i][j2 * 4 + 2], acc[i][j2 * 4 + 3]);
      *reinterpret_cast<float4*>(
          &feat[(size_t)r[i] * 128 + 4 * g + 32 * j2]) = v;
    }
  }

  // el/er epilogue: col c = 4g+32*h+m has head h (== j2); flat attn index ==
  // 32h + 4g + m == c. Partial dot per thread, reduce over the 8 g-lanes.
  float al[16], ar[16];
#pragma unroll
  for (int h = 0; h < 4; ++h) {
    const float4 a = *reinterpret_cast<const float4*>(&attn_l[4 * g + 32 * h]);
    const float4 b = *reinterpret_cast<const float4*>(&attn_r[4 * g + 32 * h]);
    al[h * 4 + 0] = a.x; al[h * 4 + 1] = a.y; al[h * 4 + 2] = a.z; al[h * 4 + 3] = a.w;
    ar[h * 4 + 0] = b.x; ar[h * 4 + 1] = b.y; ar[h * 4 + 2] = b.z; ar[h * 4 + 3] = b.w;
  }
#pragma unroll
  for (int i = 0; i < 4; ++i) {
#pragma unroll
    for (int h = 0; h < 4; ++h) {
      float pl = acc[i][h * 4 + 0] * al[h * 4 + 0] + acc[i][h * 4 + 1] * al[h * 4 + 1]
               + acc[i][h * 4 + 2] * al[h * 4 + 2] + acc[i][h * 4 + 3] * al[h * 4 + 3];
      float pr = acc[i][h * 4 + 0] * ar[h * 4 + 0] + acc[i][h * 4 + 1] * ar[h * 4 + 1]
               + acc[i][h * 4 + 2] * ar[h * 4 + 2] + acc[i][h * 4 + 3] * ar[h * 4 + 3];
#pragma unroll
      for (int d = 1; d < 8; d <<= 1) {
        pl += __shfl_xor(pl, d);
        pr += __shfl_xor(pr, d);
      }
      if (g == 0 && valid[i]) {
        el[(size_t)r[i] * 4 + h] = pl;
        er[(size_t)r[i] * 4 + h] = pr;
      }
    }
  }
}

// ---------------------------------------------------------------------------
// CSR build: histogram -> 3-kernel exclusive scan -> scatter of src ids.
// ---------------------------------------------------------------------------
__global__ void hist_kernel(const int* __restrict__ dst, int* __restrict__ deg,
                            int E) {
  for (int e = blockIdx.x * blockDim.x + threadIdx.x; e < E;
       e += gridDim.x * blockDim.x)
    atomicAdd(&deg[dst[e]], 1);
}

// chunk = 2048 per block (256 threads x 8 elems); writes per-block exclusive
// scan into offs and the block total into blk_sums.
__global__ __launch_bounds__(256) void scan_a(const int* __restrict__ deg,
                                              int* __restrict__ offs,
                                              int* __restrict__ blk_sums,
                                              int n) {
  __shared__ int wsum[4];
  const int b = blockIdx.x, t = threadIdx.x;
  const int base = b * 2048 + t * 8;
  int v[8];
  int s = 0;
#pragma unroll
  for (int j = 0; j < 8; ++j) {
    v[j] = s;
    const int d = (base + j < n) ? deg[base + j] : 0;
    s += d;
  }
  const int lane = t & 63;
  int incl = s;
#pragma unroll
  for (int d = 1; d < 64; d <<= 1) {
    const int o = __shfl_up(incl, d);
    if (lane >= d) incl += o;
  }
  const int w = t >> 6;
  if (lane == 63) wsum[w] = incl;
  __syncthreads();
  int woff = 0;
  for (int ww = 0; ww < w; ++ww) woff += wsum[ww];
  const int thr_excl = woff + incl - s;
#pragma unroll
  for (int j = 0; j < 8; ++j)
    if (base + j < n) offs[base + j] = thr_excl + v[j];
  if (t == 255) blk_sums[b] = woff + incl;
}

// single block of 64 threads; requires nb <= 64 (here nb = 49).
__global__ void scan_b(const int* __restrict__ blk_sums,
                       int* __restrict__ blk_off, int* __restrict__ offs,
                       int n, int nb) {
  const int lane = threadIdx.x & 63;
  int v = (lane < nb) ? blk_sums[lane] : 0;
  int incl = v;
#pragma unroll
  for (int d = 1; d < 64; d <<= 1) {
    const int o = __shfl_up(incl, d);
    if (lane >= d) incl += o;
  }
  if (lane < nb) blk_off[lane] = incl - v;
  if (lane == 63) offs[n] = incl;  // total edge count
}

__global__ __launch_bounds__(256) void scan_c(int* __restrict__ offs,
                                              const int* __restrict__ blk_off,
                                              int n) {
  const int b = blockIdx.x;
  const int base = b * 2048 + threadIdx.x * 8;
  const int add = blk_off[b];
#pragma unroll
  for (int j = 0; j < 8; ++j)
    if (base + j < n) offs[base + j] += add;
}

__global__ void scatter_kernel(const int* __restrict__ src,
                               const int* __restrict__ dst,
                               const int* __restrict__ offs,
                               int* __restrict__ cursor,
                               int* __restrict__ csr_src, int E) {
  for (int e = blockIdx.x * blockDim.x + threadIdx.x; e < E;
       e += gridDim.x * blockDim.x) {
    const int d = dst[e];
    const int pos = offs[d] + atomicAdd(&cursor[d], 1);
    csr_src[pos] = src[e];
  }
}

// ---------------------------------------------------------------------------
// Pull aggregation: one wave per destination node. Lane l owns output elems
// l (head l>>5) and l+64 (head l>>5 + 2). Two passes over in-edges:
// max, then exp/accumulate. Normalize at the end.
// ---------------------------------------------------------------------------
__global__ __launch_bounds__(256) void agg_kernel(
    const float* __restrict__ feat, const float* __restrict__ el,
    const float* __restrict__ er, const float* __restrict__ x,
    const float* __restrict__ bias, const int* __restrict__ offs,
    const int* __restrict__ csr_src, float* __restrict__ out, int N)
{
  const int wid = (int)((blockIdx.x * (size_t)blockDim.x + threadIdx.x) >> 6);
  const int lane = threadIdx.x & 63;
  if (wid >= N) return;
  const int n = wid;
  const int beg = offs[n], end = offs[n + 1];
  const int h0 = lane >> 5;      // head of elem `lane`
  const int h1 = h0 + 2;         // head of elem `lane+64`
  const float ern0 = er[(size_t)n * 4 + h0];
  const float ern1 = er[(size_t)n * 4 + h1];

  float m0 = -INFINITY, m1 = -INFINITY;
  for (int p = beg; p < end; ++p) {
    const int s = csr_src[p];
    float e0 = el[(size_t)s * 4 + h0] + ern0;
    float e1 = el[(size_t)s * 4 + h1] + ern1;
    e0 = e0 > 0.f ? e0 : NEG_SLOPE * e0;
    e1 = e1 > 0.f ? e1 : NEG_SLOPE * e1;
    m0 = fmaxf(m0, e0);
    m1 = fmaxf(m1, e1);
  }

  float acc0 = 0.f, acc1 = 0.f, ds0 = 0.f, ds1 = 0.f;
  for (int p = beg; p < end; ++p) {
    const int s = csr_src[p];
    float e0 = el[(size_t)s * 4 + h0] + ern0;
    float e1 = el[(size_t)s * 4 + h1] + ern1;
    e0 = e0 > 0.f ? e0 : NEG_SLOPE * e0;
    e1 = e1 > 0.f ? e1 : NEG_SLOPE * e1;
    const float w0 = __expf(e0 - m0);
    const float w1 = __expf(e1 - m1);
    const float f0 = feat[(size_t)s * 128 + lane];
    const float f1 = feat[(size_t)s * 128 + 64 + lane];
    acc0 = fmaf(w0, f0, acc0);
    acc1 = fmaf(w1, f1, acc1);
    ds0 += w0;
    ds1 += w1;
  }

  const float r0 = acc0 / fmaxf(ds0, 1e-38f);
  const float r1 = acc1 / fmaxf(ds1, 1e-38f);
  out[(size_t)n * 128 + lane]      = r0 + x[(size_t)n * 128 + lane] + bias[lane];
  out[(size_t)n * 128 + 64 + lane] = r1 + x[(size_t)n * 128 + 64 + lane] + bias[64 + lane];
}

// ---------------------------------------------------------------------------
extern "C" void kernel_launch(void* const* d_in, const int* in_sizes, int n_in,
                              void* d_out, int out_size, void* d_ws,
                              size_t ws_size, hipStream_t stream) {
  const float* x      = (const float*)d_in[0];
  const float* fc_w   = (const float*)d_in[1];
  const float* attn_l = (const float*)d_in[2];
  const float* attn_r = (const float*)d_in[3];
  const float* bias   = (const float*)d_in[4];
  const int*   src    = (const int*)d_in[5];
  const int*   dst    = (const int*)d_in[6];
  const int N = in_sizes[0] / 128;
  const int E = in_sizes[5];
  float* out = (float*)d_out;

  char* ws = (char*)d_ws;
  size_t off = 0;
  auto alloc = [&](size_t bytes) {
    void* p = ws + off;
    off += (bytes + 255) & ~(size_t)255;
    return p;
  };
  float* feat     = (float*)alloc((size_t)N * 128 * 4);
  float* el       = (float*)alloc((size_t)N * 4 * 4);
  float* er       = (float*)alloc((size_t)N * 4 * 4);
  int*   deg      = (int*)alloc((size_t)N * 4);
  int*   cursor   = (int*)alloc((size_t)N * 4);
  int*   offs     = (int*)alloc((size_t)(N + 1) * 4);
  int*   blk_sums = (int*)alloc(256);
  int*   blk_off  = (int*)alloc(256);
  int*   csr_src  = (int*)alloc((size_t)E * 4);

  hipMemsetAsync(deg, 0, (size_t)N * 4, stream);
  hipMemsetAsync(cursor, 0, (size_t)N * 4, stream);

  gemm_feat_attn<<<(N + 127) / 128, 256, 0, stream>>>(x, fc_w, attn_l, attn_r,
                                                      feat, el, er, N);
  hist_kernel<<<2048, 256, 0, stream>>>(dst, deg, E);
  const int nb = (N + 2047) / 2048;  // 49 for N=100000 (must be <= 64)
  scan_a<<<nb, 256, 0, stream>>>(deg, offs, blk_sums, N);
  scan_b<<<1, 64, 0, stream>>>(blk_sums, blk_off, offs, N, nb);
  scan_c<<<nb, 256, 0, stream>>>(offs, blk_off, N);
  scatter_kernel<<<2048, 256, 0, stream>>>(src, dst, offs, cursor, csr_src, E);
  agg_kernel<<<(N + 3) / 4, 256, 0, stream>>>(feat, el, er, x, bias, offs,
                                              csr_src, out, N);
}

// Round 2
// 355.650 us; speedup vs baseline: 1.5572x; 1.5572x over previous
//
#include <hip/hip_runtime.h>
#include <math.h>

#define NEG_SLOPE 0.2f

// ---------------------------------------------------------------------------
// GEMM: feat = x @ fc_w^T  (N x 128) = (N x 128) @ (128 x 128)^T
// fused epilogue: el[n][h] = sum_d feat[n][h*32+d]*attn_l[h][d], er likewise.
// Block = 256 threads, tile = 128 rows. fc_w staged transposed in LDS [k][c].
// ---------------------------------------------------------------------------
__global__ __launch_bounds__(256) void gemm_feat_attn(
    const float* __restrict__ x, const float* __restrict__ fc_w,
    const float* __restrict__ attn_l, const float* __restrict__ attn_r,
    float* __restrict__ feat, float* __restrict__ el, float* __restrict__ er,
    int N)
{
  __shared__ float fc_lds[128 * 128];  // [k][c]; bank = c%32 -> conflict-free
  const int t = threadIdx.x;
  for (int f = t; f < 128 * 32; f += 256) {
    const int c = f & 127, k4 = f >> 7;
    const float4 v = *reinterpret_cast<const float4*>(fc_w + c * 128 + k4 * 4);
    fc_lds[(k4 * 4 + 0) * 128 + c] = v.x;
    fc_lds[(k4 * 4 + 1) * 128 + c] = v.y;
    fc_lds[(k4 * 4 + 2) * 128 + c] = v.z;
    fc_lds[(k4 * 4 + 3) * 128 + c] = v.w;
  }
  __syncthreads();

  const int rgrp = t >> 3;  // [0,32)
  const int g = t & 7;      // [0,8)
  const int row_base = blockIdx.x * 128;

  float acc[4][16];
#pragma unroll
  for (int i = 0; i < 4; ++i)
#pragma unroll
    for (int j = 0; j < 16; ++j) acc[i][j] = 0.f;

  int r[4]; bool valid[4]; const float* xp[4];
#pragma unroll
  for (int i = 0; i < 4; ++i) {
    r[i] = row_base + rgrp + 32 * i;
    valid[i] = r[i] < N;
    xp[i] = x + (size_t)(valid[i] ? r[i] : 0) * 128;
  }

  for (int k = 0; k < 128; k += 4) {
    float4 xv[4];
#pragma unroll
    for (int i = 0; i < 4; ++i)
      xv[i] = *reinterpret_cast<const float4*>(xp[i] + k);
#pragma unroll
    for (int kk = 0; kk < 4; ++kk) {
      float4 fv[4];
#pragma unroll
      for (int j2 = 0; j2 < 4; ++j2)
        fv[j2] = *reinterpret_cast<const float4*>(
            &fc_lds[(k + kk) * 128 + 4 * g + 32 * j2]);
#pragma unroll
      for (int i = 0; i < 4; ++i) {
        const float xs = (kk == 0) ? xv[i].x : (kk == 1) ? xv[i].y
                       : (kk == 2) ? xv[i].z : xv[i].w;
#pragma unroll
        for (int j2 = 0; j2 < 4; ++j2) {
          acc[i][j2 * 4 + 0] = fmaf(xs, fv[j2].x, acc[i][j2 * 4 + 0]);
          acc[i][j2 * 4 + 1] = fmaf(xs, fv[j2].y, acc[i][j2 * 4 + 1]);
          acc[i][j2 * 4 + 2] = fmaf(xs, fv[j2].z, acc[i][j2 * 4 + 2]);
          acc[i][j2 * 4 + 3] = fmaf(xs, fv[j2].w, acc[i][j2 * 4 + 3]);
        }
      }
    }
  }

#pragma unroll
  for (int i = 0; i < 4; ++i) {
    if (!valid[i]) continue;
#pragma unroll
    for (int j2 = 0; j2 < 4; ++j2) {
      const float4 v = make_float4(acc[i][j2 * 4 + 0], acc[i][j2 * 4 + 1],
                                   acc[i][j2 * 4 + 2], acc[i][j2 * 4 + 3]);
      *reinterpret_cast<float4*>(
          &feat[(size_t)r[i] * 128 + 4 * g + 32 * j2]) = v;
    }
  }

  float al[16], ar[16];
#pragma unroll
  for (int h = 0; h < 4; ++h) {
    const float4 a = *reinterpret_cast<const float4*>(&attn_l[4 * g + 32 * h]);
    const float4 b = *reinterpret_cast<const float4*>(&attn_r[4 * g + 32 * h]);
    al[h * 4 + 0] = a.x; al[h * 4 + 1] = a.y; al[h * 4 + 2] = a.z; al[h * 4 + 3] = a.w;
    ar[h * 4 + 0] = b.x; ar[h * 4 + 1] = b.y; ar[h * 4 + 2] = b.z; ar[h * 4 + 3] = b.w;
  }
#pragma unroll
  for (int i = 0; i < 4; ++i) {
#pragma unroll
    for (int h = 0; h < 4; ++h) {
      float pl = acc[i][h * 4 + 0] * al[h * 4 + 0] + acc[i][h * 4 + 1] * al[h * 4 + 1]
               + acc[i][h * 4 + 2] * al[h * 4 + 2] + acc[i][h * 4 + 3] * al[h * 4 + 3];
      float pr = acc[i][h * 4 + 0] * ar[h * 4 + 0] + acc[i][h * 4 + 1] * ar[h * 4 + 1]
               + acc[i][h * 4 + 2] * ar[h * 4 + 2] + acc[i][h * 4 + 3] * ar[h * 4 + 3];
#pragma unroll
      for (int d = 1; d < 8; d <<= 1) {
        pl += __shfl_xor(pl, d);
        pr += __shfl_xor(pr, d);
      }
      if (g == 0 && valid[i]) {
        el[(size_t)r[i] * 4 + h] = pl;
        er[(size_t)r[i] * 4 + h] = pr;
      }
    }
  }
}

// ---------------------------------------------------------------------------
// CSR build: histogram -> 3-kernel exclusive scan -> scatter.
// ---------------------------------------------------------------------------
__global__ void hist_kernel(const int* __restrict__ dst, int* __restrict__ deg,
                            int E) {
  for (int e = blockIdx.x * blockDim.x + threadIdx.x; e < E;
       e += gridDim.x * blockDim.x)
    atomicAdd(&deg[dst[e]], 1);
}

__global__ __launch_bounds__(256) void scan_a(const int* __restrict__ deg,
                                              int* __restrict__ offs,
                                              int* __restrict__ blk_sums,
                                              int n) {
  __shared__ int wsum[4];
  const int b = blockIdx.x, t = threadIdx.x;
  const int base = b * 2048 + t * 8;
  int v[8];
  int s = 0;
#pragma unroll
  for (int j = 0; j < 8; ++j) {
    v[j] = s;
    const int d = (base + j < n) ? deg[base + j] : 0;
    s += d;
  }
  const int lane = t & 63;
  int incl = s;
#pragma unroll
  for (int d = 1; d < 64; d <<= 1) {
    const int o = __shfl_up(incl, d);
    if (lane >= d) incl += o;
  }
  const int w = t >> 6;
  if (lane == 63) wsum[w] = incl;
  __syncthreads();
  int woff = 0;
  for (int ww = 0; ww < w; ++ww) woff += wsum[ww];
  const int thr_excl = woff + incl - s;
#pragma unroll
  for (int j = 0; j < 8; ++j)
    if (base + j < n) offs[base + j] = thr_excl + v[j];
  if (t == 255) blk_sums[b] = woff + incl;
}

__global__ void scan_b(const int* __restrict__ blk_sums,
                       int* __restrict__ blk_off, int* __restrict__ offs,
                       int n, int nb) {
  const int lane = threadIdx.x & 63;
  int v = (lane < nb) ? blk_sums[lane] : 0;
  int incl = v;
#pragma unroll
  for (int d = 1; d < 64; d <<= 1) {
    const int o = __shfl_up(incl, d);
    if (lane >= d) incl += o;
  }
  if (lane < nb) blk_off[lane] = incl - v;
  if (lane == 63) offs[n] = incl;
}

__global__ __launch_bounds__(256) void scan_c(int* __restrict__ offs,
                                              const int* __restrict__ blk_off,
                                              int n) {
  const int b = blockIdx.x;
  const int base = b * 2048 + threadIdx.x * 8;
  const int add = blk_off[b];
#pragma unroll
  for (int j = 0; j < 8; ++j)
    if (base + j < n) offs[base + j] += add;
}

__device__ __forceinline__ float lrelu_exp(float v) {
  v = v > 0.f ? v : NEG_SLOPE * v;
  return __expf(v);  // no max-subtraction: |v| <~ 10, fp32-safe; result is
                     // normalized by the denominator so it matches reference
}

// Scatter src ids AND per-edge-head softmax numerators w = exp(lrelu(el+er))
// into CSR order. atomicAdd on offs turns it into end-offsets (beg = end-deg).
__global__ void scatter_kernel(const int* __restrict__ src,
                               const int* __restrict__ dst,
                               const float* __restrict__ el,
                               const float* __restrict__ er,
                               int* __restrict__ offs,
                               int* __restrict__ csr_src,
                               float* __restrict__ wscore, int E) {
  for (int e = blockIdx.x * blockDim.x + threadIdx.x; e < E;
       e += gridDim.x * blockDim.x) {
    const int d = dst[e];
    const int s = src[e];
    const int pos = atomicAdd(&offs[d], 1);
    csr_src[pos] = s;
    const float4 l4 = *reinterpret_cast<const float4*>(el + (size_t)s * 4);
    const float4 r4 = *reinterpret_cast<const float4*>(er + (size_t)d * 4);
    float4 w;
    w.x = lrelu_exp(l4.x + r4.x);
    w.y = lrelu_exp(l4.y + r4.y);
    w.z = lrelu_exp(l4.z + r4.z);
    w.w = lrelu_exp(l4.w + r4.w);
    *reinterpret_cast<float4*>(wscore + (size_t)pos * 4) = w;
  }
}

// ---------------------------------------------------------------------------
// Pull aggregation: one wave per destination node. Lane l owns output elems
// {2l, 2l+1}, single head h = l>>4. Single pass: acc += w * feat2[src],
// ds += w, normalize at the end. 4-edge predicated unroll for MLP.
// ---------------------------------------------------------------------------
__global__ __launch_bounds__(256) void agg_kernel(
    const float* __restrict__ feat, const float* __restrict__ x,
    const float* __restrict__ bias, const int* __restrict__ end_offs,
    const int* __restrict__ deg, const int* __restrict__ csr_src,
    const float* __restrict__ wscore, float* __restrict__ out, int N)
{
  const int n = (int)((blockIdx.x * (size_t)blockDim.x + threadIdx.x) >> 6);
  if (n >= N) return;
  const int lane = threadIdx.x & 63;
  const int h = lane >> 4;
  const int end = end_offs[n];
  const int beg = end - deg[n];
  const float2* __restrict__ feat2 = (const float2*)feat;

  float ax = 0.f, ay = 0.f, ds = 0.f;
  for (int p = beg; p < end; p += 4) {
    const int last = end - 1;
    const int e1 = min(p + 1, last);
    const int e2 = min(p + 2, last);
    const int e3 = min(p + 3, last);
    const int s0 = csr_src[p];
    const int s1 = csr_src[e1];
    const int s2 = csr_src[e2];
    const int s3 = csr_src[e3];
    float w0 = wscore[(size_t)p * 4 + h];
    float w1 = wscore[(size_t)e1 * 4 + h];
    float w2 = wscore[(size_t)e2 * 4 + h];
    float w3 = wscore[(size_t)e3 * 4 + h];
    const float2 f0 = feat2[(size_t)s0 * 64 + lane];
    const float2 f1 = feat2[(size_t)s1 * 64 + lane];
    const float2 f2 = feat2[(size_t)s2 * 64 + lane];
    const float2 f3 = feat2[(size_t)s3 * 64 + lane];
    if (p + 1 >= end) w1 = 0.f;
    if (p + 2 >= end) w2 = 0.f;
    if (p + 3 >= end) w3 = 0.f;
    ax = fmaf(w0, f0.x, ax); ay = fmaf(w0, f0.y, ay);
    ax = fmaf(w1, f1.x, ax); ay = fmaf(w1, f1.y, ay);
    ax = fmaf(w2, f2.x, ax); ay = fmaf(w2, f2.y, ay);
    ax = fmaf(w3, f3.x, ax); ay = fmaf(w3, f3.y, ay);
    ds += (w0 + w1) + (w2 + w3);
  }

  const float inv = 1.f / fmaxf(ds, 1e-38f);
  const float2 xr = ((const float2*)x)[(size_t)n * 64 + lane];
  const float2 br = ((const float2*)bias)[lane];
  float2 o;
  o.x = fmaf(ax, inv, xr.x + br.x);
  o.y = fmaf(ay, inv, xr.y + br.y);
  ((float2*)out)[(size_t)n * 64 + lane] = o;
}

// ---------------------------------------------------------------------------
extern "C" void kernel_launch(void* const* d_in, const int* in_sizes, int n_in,
                              void* d_out, int out_size, void* d_ws,
                              size_t ws_size, hipStream_t stream) {
  const float* x      = (const float*)d_in[0];
  const float* fc_w   = (const float*)d_in[1];
  const float* attn_l = (const float*)d_in[2];
  const float* attn_r = (const float*)d_in[3];
  const float* bias   = (const float*)d_in[4];
  const int*   src    = (const int*)d_in[5];
  const int*   dst    = (const int*)d_in[6];
  const int N = in_sizes[0] / 128;
  const int E = in_sizes[5];
  float* out = (float*)d_out;

  char* ws = (char*)d_ws;
  size_t off = 0;
  auto alloc = [&](size_t bytes) {
    void* p = ws + off;
    off += (bytes + 255) & ~(size_t)255;
    return p;
  };
  float* feat     = (float*)alloc((size_t)N * 128 * 4);
  float* el       = (float*)alloc((size_t)N * 4 * 4);
  float* er       = (float*)alloc((size_t)N * 4 * 4);
  int*   deg      = (int*)alloc((size_t)N * 4);
  int*   offs     = (int*)alloc((size_t)(N + 1) * 4);
  int*   blk_sums = (int*)alloc(256);
  int*   blk_off  = (int*)alloc(256);
  float* wscore   = (float*)alloc((size_t)E * 4 * 4);
  int*   csr_src  = (int*)alloc((size_t)E * 4);

  hipMemsetAsync(deg, 0, (size_t)N * 4, stream);

  gemm_feat_attn<<<(N + 127) / 128, 256, 0, stream>>>(x, fc_w, attn_l, attn_r,
                                                      feat, el, er, N);
  hist_kernel<<<2048, 256, 0, stream>>>(dst, deg, E);
  const int nb = (N + 2047) / 2048;  // 49 for N=100000 (must be <= 64)
  scan_a<<<nb, 256, 0, stream>>>(deg, offs, blk_sums, N);
  scan_b<<<1, 64, 0, stream>>>(blk_sums, blk_off, offs, N, nb);
  scan_c<<<nb, 256, 0, stream>>>(offs, blk_off, N);
  scatter_kernel<<<2048, 256, 0, stream>>>(src, dst, el, er, offs, csr_src,
                                           wscore, E);
  // offs now holds END offsets (beg = end - deg)
  agg_kernel<<<(N + 3) / 4, 256, 0, stream>>>(feat, x, bias, offs, deg,
                                              csr_src, wscore, out, N);
}